// Round 1
// baseline (2795.234 us; speedup 1.0000x reference)
//
#include <hip/hip_runtime.h>
#include <hip/hip_bf16.h>
#include <cstddef>

// Problem constants
#define NN 2048      // nodes
#define CIN 2
#define HH 32        // hidden
#define EMB 16
#define HOR 12
#define BB 32        // batch
#define TT 16        // time steps
#define GC (4*HH)    // 128 gate channels
#define XCOLS (BB*TT*CIN)   // 1024
#define HCOLS (BB*HH)       // 1024

// ---------------------------------------------------------------------------
// Kernel 1: A = softmax(relu(E1 @ E2^T)) row-wise. One block per row.
// ---------------------------------------------------------------------------
__global__ __launch_bounds__(256) void adj_softmax(const float* __restrict__ E1,
                                                   const float* __restrict__ E2,
                                                   float* __restrict__ A) {
    const int i = blockIdx.x;
    __shared__ float red[256];
    float e1[EMB];
#pragma unroll
    for (int k = 0; k < EMB; ++k) e1[k] = E1[i * EMB + k];

    float s[8];
    float mx = -1e30f;
#pragma unroll
    for (int q = 0; q < 8; ++q) {
        const int j = q * 256 + threadIdx.x;
        float d = 0.f;
#pragma unroll
        for (int k = 0; k < EMB; ++k) d += e1[k] * E2[j * EMB + k];
        d = fmaxf(d, 0.0f);          // relu
        s[q] = d;
        mx = fmaxf(mx, d);
    }
    red[threadIdx.x] = mx;
    __syncthreads();
    for (int off = 128; off > 0; off >>= 1) {
        if (threadIdx.x < off) red[threadIdx.x] = fmaxf(red[threadIdx.x], red[threadIdx.x + off]);
        __syncthreads();
    }
    mx = red[0];
    __syncthreads();

    float sum = 0.f;
#pragma unroll
    for (int q = 0; q < 8; ++q) { s[q] = expf(s[q] - mx); sum += s[q]; }
    red[threadIdx.x] = sum;
    __syncthreads();
    for (int off = 128; off > 0; off >>= 1) {
        if (threadIdx.x < off) red[threadIdx.x] += red[threadIdx.x + off];
        __syncthreads();
    }
    const float inv = 1.0f / red[0];
#pragma unroll
    for (int q = 0; q < 8; ++q)
        A[(size_t)i * NN + q * 256 + threadIdx.x] = s[q] * inv;
}

// ---------------------------------------------------------------------------
// Kernel 2: Xc[j][(b*T+t)*C+c] = x[b][t][j][c]   (node-major transpose)
// ---------------------------------------------------------------------------
__global__ __launch_bounds__(256) void transpose_x(const float* __restrict__ x,
                                                   float* __restrict__ Xc) {
    const int idx = blockIdx.x * 256 + threadIdx.x;    // over NN*XCOLS
    const int j  = idx >> 10;          // node
    const int m  = idx & 1023;         // (b*T+t)*C + c
    const int c  = m & 1;
    const int bt = m >> 1;
    Xc[idx] = x[((size_t)bt * NN + j) * CIN + c];
}

// ---------------------------------------------------------------------------
// Kernel 3: fp32 GEMM  C[M,N] = A[M,K] * B[K,N]  (row-major, all dims %64==0)
// 64x64 tile, BK=16, 256 threads, 4x4 microtile.
// ---------------------------------------------------------------------------
#define TILE 64
#define BK 16
__global__ __launch_bounds__(256) void gemm_f32(const float* __restrict__ A,
                                                const float* __restrict__ Bm,
                                                float* __restrict__ C,
                                                int M, int N, int K) {
    __shared__ float As[BK][TILE + 4];   // [k][i]; +4 pad keeps 16B align & kills conflicts
    __shared__ float Bs[BK][TILE];       // [k][j]
    const int tx = threadIdx.x & 15;
    const int ty = threadIdx.x >> 4;
    const int row0 = blockIdx.y * TILE;
    const int col0 = blockIdx.x * TILE;

    float acc[4][4] = {};

    for (int k0 = 0; k0 < K; k0 += BK) {
        // stage A tile: 64 rows x 16 k
        {
            const int i  = threadIdx.x >> 2;
            const int kq = (threadIdx.x & 3) * 4;
            const float4 v = *(const float4*)(A + (size_t)(row0 + i) * K + k0 + kq);
            As[kq + 0][i] = v.x; As[kq + 1][i] = v.y;
            As[kq + 2][i] = v.z; As[kq + 3][i] = v.w;
        }
        // stage B tile: 16 k x 64 cols
        {
            const int k  = threadIdx.x >> 4;
            const int jq = (threadIdx.x & 15) * 4;
            *(float4*)&Bs[k][jq] = *(const float4*)(Bm + (size_t)(k0 + k) * N + col0 + jq);
        }
        __syncthreads();
#pragma unroll
        for (int k = 0; k < BK; ++k) {
            float a[4], b[4];
            *(float4*)a = *(const float4*)&As[k][ty * 4];
            *(float4*)b = *(const float4*)&Bs[k][tx * 4];
#pragma unroll
            for (int ii = 0; ii < 4; ++ii)
#pragma unroll
                for (int jj = 0; jj < 4; ++jj)
                    acc[ii][jj] += a[ii] * b[jj];
        }
        __syncthreads();
    }
#pragma unroll
    for (int ii = 0; ii < 4; ++ii) {
        float4 v = make_float4(acc[ii][0], acc[ii][1], acc[ii][2], acc[ii][3]);
        *(float4*)(C + (size_t)(row0 + ty * 4 + ii) * N + col0 + tx * 4) = v;
    }
}

// ---------------------------------------------------------------------------
// Kernel 4: per-(node,batch) gate compute + LSTM cell update.
// gates[g] = bx[g]+bh[g] + ax0*Wx[0][g] + ax1*Wx[1][g] + sum_k ah[k]*Wh[k][g]
// ---------------------------------------------------------------------------
__global__ __launch_bounds__(128) void gate_update(const float* __restrict__ AX,  // [NN][XCOLS]
                                                   const float* __restrict__ Ah,  // [NN][HCOLS]
                                                   const float* __restrict__ Wx,  // [2][128]
                                                   const float* __restrict__ bx,  // [128]
                                                   const float* __restrict__ Wh,  // [32][128]
                                                   const float* __restrict__ bh,  // [128]
                                                   float* __restrict__ h,         // [NN][BB][HH]
                                                   float* __restrict__ c,         // [NN][BB][HH]
                                                   int t, int first) {
    const int n = blockIdx.x >> 5;
    const int b = blockIdx.x & 31;
    const int g = threadIdx.x;   // 0..127
    __shared__ float ah[HH];
    __shared__ float gs[GC];

    if (!first) {
        if (g < HH) ah[g] = Ah[(size_t)n * HCOLS + b * HH + g];
        __syncthreads();
    }
    const float ax0 = AX[(size_t)n * XCOLS + (b * TT + t) * CIN + 0];
    const float ax1 = AX[(size_t)n * XCOLS + (b * TT + t) * CIN + 1];
    float acc = bx[g] + bh[g] + ax0 * Wx[g] + ax1 * Wx[GC + g];
    if (!first) {
#pragma unroll 8
        for (int k = 0; k < HH; ++k) acc += ah[k] * Wh[k * GC + g];
    }
    gs[g] = (g < 96) ? (1.0f / (1.0f + expf(-acc))) : tanhf(acc);
    __syncthreads();
    if (g < HH) {
        const float i_ = gs[g], f_ = gs[g + 32], o_ = gs[g + 64], gg = gs[g + 96];
        const float c_old = first ? 0.0f : c[(size_t)n * HCOLS + b * HH + g];
        const float c_t = f_ * c_old + i_ * gg;
        const float h_t = o_ * tanhf(c_t);
        c[(size_t)n * HCOLS + b * HH + g] = c_t;
        h[(size_t)n * HCOLS + b * HH + g] = h_t;
    }
}

// ---------------------------------------------------------------------------
// Kernel 5: out[b][th][n] = bp[th] + sum_k h[n][b][k] * Wp[k][th]
// ---------------------------------------------------------------------------
__global__ __launch_bounds__(256) void head_kernel(const float* __restrict__ h,
                                                   const float* __restrict__ Wp,  // [32][12]
                                                   const float* __restrict__ bp,  // [12]
                                                   float* __restrict__ out) {
    const int idx = blockIdx.x * 256 + threadIdx.x;   // over BB*NN, n minor
    const int b = idx >> 11;
    const int n = idx & (NN - 1);
    float hv[HH];
    const float* hp = h + (size_t)n * HCOLS + b * HH;
#pragma unroll
    for (int k = 0; k < HH; ++k) hv[k] = hp[k];
#pragma unroll
    for (int th = 0; th < HOR; ++th) {
        float acc = bp[th];
#pragma unroll
        for (int k = 0; k < HH; ++k) acc += hv[k] * Wp[k * HOR + th];
        out[((size_t)b * HOR + th) * NN + n] = acc;
    }
}

// ---------------------------------------------------------------------------
extern "C" void kernel_launch(void* const* d_in, const int* in_sizes, int n_in,
                              void* d_out, int out_size, void* d_ws, size_t ws_size,
                              hipStream_t stream) {
    const float* x  = (const float*)d_in[0];
    const float* E1 = (const float*)d_in[1];
    const float* E2 = (const float*)d_in[2];
    const float* Wx = (const float*)d_in[3];
    const float* bx = (const float*)d_in[4];
    const float* Wh = (const float*)d_in[5];
    const float* bh = (const float*)d_in[6];
    const float* Wp = (const float*)d_in[7];
    const float* bp = (const float*)d_in[8];

    float* ws = (float*)d_ws;
    float* A  = ws;                        // 2048*2048
    float* Xc = A  + (size_t)NN * NN;      // 2048*1024
    float* AX = Xc + (size_t)NN * XCOLS;   // 2048*1024
    float* h  = AX + (size_t)NN * XCOLS;   // 2048*1024
    float* c  = h  + (size_t)NN * HCOLS;   // 2048*1024
    float* Ah = c  + (size_t)NN * HCOLS;   // 2048*1024

    adj_softmax<<<NN, 256, 0, stream>>>(E1, E2, A);
    transpose_x<<<(NN * XCOLS) / 256, 256, 0, stream>>>(x, Xc);

    dim3 gg(XCOLS / TILE, NN / TILE);   // 16 x 32
    gemm_f32<<<gg, 256, 0, stream>>>(A, Xc, AX, NN, XCOLS, NN);

    for (int t = 0; t < TT; ++t) {
        if (t > 0)
            gemm_f32<<<gg, 256, 0, stream>>>(A, h, Ah, NN, HCOLS, NN);
        gate_update<<<NN * BB, 128, 0, stream>>>(AX, Ah, Wx, bx, Wh, bh, h, c, t, t == 0 ? 1 : 0);
    }

    head_kernel<<<(BB * NN) / 256, 256, 0, stream>>>(h, Wp, bp, (float*)d_out);
}

// Round 2
// 2621.587 us; speedup vs baseline: 1.0662x; 1.0662x over previous
//
#include <hip/hip_runtime.h>
#include <hip/hip_bf16.h>
#include <cstddef>
#include <cstdint>

#define NN 2048      // nodes (M and K of the big GEMMs)
#define CIN 2
#define HH 32        // hidden
#define EMB 16
#define HOR 12
#define BB 32        // batch
#define TT 16        // time steps
#define GC 128       // 4*HH gate channels
#define XCOLS 1024   // B*T*C
#define HCOLS 1024   // B*H  (GEMM N dim)

typedef __attribute__((ext_vector_type(8))) short bf16x8;
typedef __attribute__((ext_vector_type(4))) float f32x4;
typedef unsigned short u16;

__device__ inline u16 f2bf(float f) {
    __hip_bfloat16 h = __float2bfloat16(f);
    return *reinterpret_cast<u16*>(&h);
}
__device__ inline float bf2f(u16 u) {
    __hip_bfloat16 h = *reinterpret_cast<__hip_bfloat16*>(&u);
    return __bfloat162float(h);
}
__device__ inline void split_bf(float v, u16& hi, u16& lo) {
    hi = f2bf(v);
    lo = f2bf(v - bf2f(hi));   // v-hi exact in fp32 (hi within 2^-8 of v)
}

// ---------------------------------------------------------------------------
// Kernel 1: A = softmax(relu(E1 @ E2^T)) row-wise -> bf16 hi/lo split arrays.
// ---------------------------------------------------------------------------
__global__ __launch_bounds__(256) void adj_softmax(const float* __restrict__ E1,
                                                   const float* __restrict__ E2,
                                                   u16* __restrict__ Ahi,
                                                   u16* __restrict__ Alo) {
    const int i = blockIdx.x;
    __shared__ float red[256];
    float e1[EMB];
#pragma unroll
    for (int k = 0; k < EMB; ++k) e1[k] = E1[i * EMB + k];

    float s[8];
    float mx = -1e30f;
#pragma unroll
    for (int q = 0; q < 8; ++q) {
        const int j = q * 256 + threadIdx.x;
        float d = 0.f;
#pragma unroll
        for (int k = 0; k < EMB; ++k) d += e1[k] * E2[j * EMB + k];
        d = fmaxf(d, 0.0f);
        s[q] = d;
        mx = fmaxf(mx, d);
    }
    red[threadIdx.x] = mx;
    __syncthreads();
    for (int off = 128; off > 0; off >>= 1) {
        if (threadIdx.x < off) red[threadIdx.x] = fmaxf(red[threadIdx.x], red[threadIdx.x + off]);
        __syncthreads();
    }
    mx = red[0];
    __syncthreads();

    float sum = 0.f;
#pragma unroll
    for (int q = 0; q < 8; ++q) { s[q] = expf(s[q] - mx); sum += s[q]; }
    red[threadIdx.x] = sum;
    __syncthreads();
    for (int off = 128; off > 0; off >>= 1) {
        if (threadIdx.x < off) red[threadIdx.x] += red[threadIdx.x + off];
        __syncthreads();
    }
    const float inv = 1.0f / red[0];
#pragma unroll
    for (int q = 0; q < 8; ++q) {
        const float v = s[q] * inv;
        u16 hi, lo; split_bf(v, hi, lo);
        const size_t off = (size_t)i * NN + q * 256 + threadIdx.x;
        Ahi[off] = hi; Alo[off] = lo;
    }
}

// ---------------------------------------------------------------------------
// Kernel 2: XT[col][node] bf16 hi/lo, col = (b*T+t)*C + c   ("B^T" layout)
// ---------------------------------------------------------------------------
__global__ __launch_bounds__(256) void transpose_x(const float* __restrict__ x,
                                                   u16* __restrict__ XTh,
                                                   u16* __restrict__ XTl) {
    const int idx = blockIdx.x * 256 + threadIdx.x;  // over XCOLS*NN, node minor
    const int col = idx >> 11;
    const int j   = idx & (NN - 1);
    const int bt  = col >> 1;
    const int c   = col & 1;
    const float v = x[((size_t)bt * NN + j) * CIN + c];
    u16 hi, lo; split_bf(v, hi, lo);
    XTh[idx] = hi; XTl[idx] = lo;
}

// ---------------------------------------------------------------------------
// Kernel 3: bf16x3 split MFMA GEMM.
// C[2048][1024] = A[2048][2048] * B[2048][1024], fp32 out.
// A given as row-major bf16 hi/lo; B given TRANSPOSED ([1024][2048]) hi/lo.
// C = Ahi*Bhi + Ahi*Blo + Alo*Bhi  (fp32 MFMA accumulation).
// 64x64 tile, BK=32, 256 threads (4 waves, each 32x32 = 2x2 of 16x16x32).
// LDS layout per operand-split: [kblock(4)][row(64)][16B] - conflict-free.
// ---------------------------------------------------------------------------
__global__ __launch_bounds__(256) void gemm3(const u16* __restrict__ Ahi_,
                                             const u16* __restrict__ Alo_,
                                             const u16* __restrict__ Bhi_,
                                             const u16* __restrict__ Blo_,
                                             float* __restrict__ C) {
    __shared__ char smem[16384];  // 4 chunks of 4KB: Ahi, Alo, Bhi, Blo
    const int tid  = threadIdx.x;
    const int w    = tid >> 6;
    const int lane = tid & 63;
    const int m0 = blockIdx.y * 64;
    const int n0 = blockIdx.x * 64;

    // --- staging setup: this wave handles chunks w*4 .. w*4+3 -------------
    const u16* gsrc[4];
    char*      ldst[4];
#pragma unroll
    for (int j = 0; j < 4; ++j) {
        const int ch  = w * 4 + j;
        const int kq  = ch & 3;
        const int sel = ch >> 2;          // 0 Ahi, 1 Alo, 2 Bhi, 3 Blo
        const u16* base = (sel == 0) ? Ahi_ : (sel == 1) ? Alo_ : (sel == 2) ? Bhi_ : Blo_;
        const int  r0   = (sel < 2) ? m0 : n0;
        gsrc[j] = base + (size_t)(r0 + lane) * NN + kq * 8;
        ldst[j] = smem + ch * 1024;       // wave-uniform LDS base
    }

    // --- fragment read offsets --------------------------------------------
    const int q  = lane >> 4;     // k-block
    const int mr = lane & 15;     // row/col within 16-tile
    const int wr = (w >> 1) * 32; // wave row offset in tile
    const int wc = (w & 1) * 32;  // wave col offset in tile
    int aoff[2][2], boff[2][2];
#pragma unroll
    for (int i = 0; i < 2; ++i)
#pragma unroll
        for (int s = 0; s < 2; ++s) {
            aoff[i][s] = s * 4096 + q * 1024 + (wr + i * 16 + mr) * 16;
            boff[i][s] = 8192 + s * 4096 + q * 1024 + (wc + i * 16 + mr) * 16;
        }

    f32x4 acc[2][2];
#pragma unroll
    for (int i = 0; i < 2; ++i)
#pragma unroll
        for (int j = 0; j < 2; ++j) acc[i][j] = (f32x4)(0.0f);

    for (int it = 0; it < NN / 32; ++it) {
#pragma unroll
        for (int j = 0; j < 4; ++j) {
            __builtin_amdgcn_global_load_lds(
                (const __attribute__((address_space(1))) unsigned int*)(gsrc[j]),
                (__attribute__((address_space(3))) unsigned int*)(ldst[j]), 16, 0, 0);
            gsrc[j] += 32;   // advance 32 bf16 = 64 B along K
        }
        __syncthreads();

        bf16x8 fa[2][2], fb[2][2];
#pragma unroll
        for (int i = 0; i < 2; ++i)
#pragma unroll
            for (int s = 0; s < 2; ++s) {
                fa[i][s] = *reinterpret_cast<const bf16x8*>(smem + aoff[i][s]);
                fb[i][s] = *reinterpret_cast<const bf16x8*>(smem + boff[i][s]);
            }
#pragma unroll
        for (int i = 0; i < 2; ++i)
#pragma unroll
            for (int j = 0; j < 2; ++j) {
                acc[i][j] = __builtin_amdgcn_mfma_f32_16x16x32_bf16(fa[i][0], fb[j][0], acc[i][j], 0, 0, 0);
                acc[i][j] = __builtin_amdgcn_mfma_f32_16x16x32_bf16(fa[i][0], fb[j][1], acc[i][j], 0, 0, 0);
                acc[i][j] = __builtin_amdgcn_mfma_f32_16x16x32_bf16(fa[i][1], fb[j][0], acc[i][j], 0, 0, 0);
            }
        __syncthreads();
    }

    // --- epilogue: C/D layout col=lane&15, row=quad*4+reg ------------------
#pragma unroll
    for (int i = 0; i < 2; ++i)
#pragma unroll
        for (int j = 0; j < 2; ++j)
#pragma unroll
            for (int r = 0; r < 4; ++r) {
                const int row = m0 + wr + i * 16 + q * 4 + r;
                const int col = n0 + wc + j * 16 + mr;
                C[(size_t)row * HCOLS + col] = acc[i][j][r];
            }
}

// ---------------------------------------------------------------------------
// Kernel 4: gates + LSTM cell update for a 64-node x 1-batch slab.
// grid = (NN/64, BB). Writes h (fp32, [node][b*H+h]) and hT hi/lo
// ([b*H+h][node] bf16) for the next recurrent GEMM.
// ---------------------------------------------------------------------------
__global__ __launch_bounds__(256) void gate_update(const float* __restrict__ AX,   // [NN][XCOLS]
                                                   const float* __restrict__ Ahm,  // [NN][HCOLS]
                                                   const float* __restrict__ Wx,   // [2][128]
                                                   const float* __restrict__ bx,
                                                   const float* __restrict__ Wh,   // [32][128]
                                                   const float* __restrict__ bh,
                                                   float* __restrict__ c,          // [NN][HCOLS]
                                                   float* __restrict__ h32,        // [NN][HCOLS]
                                                   u16* __restrict__ hTh,          // [HCOLS][NN]
                                                   u16* __restrict__ hTl,
                                                   int t, int first) {
    const int n0 = blockIdx.x * 64;
    const int b  = blockIdx.y;
    const int tid = threadIdx.x;
    __shared__ float ah_s[64][33];
    __shared__ float gs[64][133];
    __shared__ float axs[2][64];

    if (!first) {
        const int nl = tid >> 2;
        const int kq = (tid & 3) * 8;
        const float* src = Ahm + (size_t)(n0 + nl) * HCOLS + b * HH + kq;
        const float4 v0 = *(const float4*)src;
        const float4 v1 = *(const float4*)(src + 4);
        ah_s[nl][kq + 0] = v0.x; ah_s[nl][kq + 1] = v0.y;
        ah_s[nl][kq + 2] = v0.z; ah_s[nl][kq + 3] = v0.w;
        ah_s[nl][kq + 4] = v1.x; ah_s[nl][kq + 5] = v1.y;
        ah_s[nl][kq + 6] = v1.z; ah_s[nl][kq + 7] = v1.w;
    }
    if (tid < 128) {
        const int which = tid >> 6, nl = tid & 63;
        axs[which][nl] = AX[(size_t)(n0 + nl) * XCOLS + (b * TT + t) * CIN + which];
    }
    __syncthreads();

    const int qg = tid >> 6;   // gate-type quadrant (wave-uniform)
    const int nl = tid & 63;
    const float ax0 = axs[0][nl], ax1 = axs[1][nl];
    float acc[32];
#pragma unroll
    for (int g = 0; g < 32; ++g) {
        const int gg = qg * 32 + g;
        acc[g] = bx[gg] + bh[gg] + ax0 * Wx[gg] + ax1 * Wx[GC + gg];
    }
    if (!first) {
#pragma unroll 8
        for (int k = 0; k < HH; ++k) {
            const float a = ah_s[nl][k];
            const float* wrow = Wh + k * GC + qg * 32;   // wave-uniform -> s_load
#pragma unroll
            for (int g4 = 0; g4 < 8; ++g4) {
                const float4 wv = *(const float4*)(wrow + g4 * 4);
                acc[g4 * 4 + 0] += a * wv.x;
                acc[g4 * 4 + 1] += a * wv.y;
                acc[g4 * 4 + 2] += a * wv.z;
                acc[g4 * 4 + 3] += a * wv.w;
            }
        }
    }
#pragma unroll
    for (int g = 0; g < 32; ++g) {
        const float v = acc[g];
        gs[nl][qg * 32 + g] = (qg < 3) ? (1.0f / (1.0f + expf(-v))) : tanhf(v);
    }
    __syncthreads();

    const int hq = tid >> 6;
#pragma unroll
    for (int u = 0; u < 8; ++u) {
        const int hidx = hq * 8 + u;
        const float i_ = gs[nl][hidx];
        const float f_ = gs[nl][32 + hidx];
        const float o_ = gs[nl][64 + hidx];
        const float g_ = gs[nl][96 + hidx];
        const size_t off = (size_t)(n0 + nl) * HCOLS + b * HH + hidx;
        const float c_old = first ? 0.0f : c[off];
        const float c_t = f_ * c_old + i_ * g_;
        const float h_t = o_ * tanhf(c_t);
        c[off] = c_t;
        h32[off] = h_t;
        u16 hh, hl; split_bf(h_t, hh, hl);
        const size_t toff = (size_t)(b * HH + hidx) * NN + n0 + nl;
        hTh[toff] = hh; hTl[toff] = hl;
    }
}

// ---------------------------------------------------------------------------
// Kernel 5: out[b][th][n] = bp[th] + sum_k h[n][b*H+k] * Wp[k][th]
// ---------------------------------------------------------------------------
__global__ __launch_bounds__(256) void head_kernel(const float* __restrict__ h,
                                                   const float* __restrict__ Wp,
                                                   const float* __restrict__ bp,
                                                   float* __restrict__ out) {
    const int idx = blockIdx.x * 256 + threadIdx.x;   // over BB*NN, n minor
    const int b = idx >> 11;
    const int n = idx & (NN - 1);
    float hv[HH];
    const float* hp = h + (size_t)n * HCOLS + b * HH;
#pragma unroll
    for (int k = 0; k < HH; ++k) hv[k] = hp[k];
#pragma unroll
    for (int th = 0; th < HOR; ++th) {
        float acc = bp[th];
#pragma unroll
        for (int k = 0; k < HH; ++k) acc += hv[k] * Wp[k * HOR + th];
        out[((size_t)b * HOR + th) * NN + n] = acc;
    }
}

// ---------------------------------------------------------------------------
extern "C" void kernel_launch(void* const* d_in, const int* in_sizes, int n_in,
                              void* d_out, int out_size, void* d_ws, size_t ws_size,
                              hipStream_t stream) {
    const float* x  = (const float*)d_in[0];
    const float* E1 = (const float*)d_in[1];
    const float* E2 = (const float*)d_in[2];
    const float* Wx = (const float*)d_in[3];
    const float* bx = (const float*)d_in[4];
    const float* Wh = (const float*)d_in[5];
    const float* bh = (const float*)d_in[6];
    const float* Wp = (const float*)d_in[7];
    const float* bp = (const float*)d_in[8];

    // workspace layout (bytes)
    char* ws = (char*)d_ws;
    u16*   A_hi = (u16*)(ws);                         //  8 MB  [2048][2048] bf16
    u16*   A_lo = (u16*)(ws + (8u << 20));            //  8 MB
    u16*   XTh  = (u16*)(ws + (16u << 20));           //  4 MB  [1024][2048] bf16
    u16*   XTl  = (u16*)(ws + (20u << 20));           //  4 MB
    float* AX   = (float*)(ws + (24u << 20));         //  8 MB  [2048][1024] f32
    float* Ahm  = (float*)(ws + (32u << 20));         //  8 MB
    float* cst  = (float*)(ws + (40u << 20));         //  8 MB
    float* h32  = (float*)(ws + (48u << 20));         //  8 MB
    // hT aliases the XT region (XT dead after the x-GEMM; first hT write is later)
    u16*   hTh  = XTh;
    u16*   hTl  = XTl;

    adj_softmax<<<NN, 256, 0, stream>>>(E1, E2, A_hi, A_lo);
    transpose_x<<<(XCOLS * NN) / 256, 256, 0, stream>>>(x, XTh, XTl);

    dim3 gg(HCOLS / 64, NN / 64);   // 16 x 32 = 512 blocks
    gemm3<<<gg, 256, 0, stream>>>(A_hi, A_lo, XTh, XTl, AX);

    for (int t = 0; t < TT; ++t) {
        if (t > 0)
            gemm3<<<gg, 256, 0, stream>>>(A_hi, A_lo, hTh, hTl, Ahm);
        gate_update<<<dim3(NN / 64, BB), 256, 0, stream>>>(AX, Ahm, Wx, bx, Wh, bh,
                                                           cst, h32, hTh, hTl, t, t == 0 ? 1 : 0);
    }

    head_kernel<<<(BB * NN) / 256, 256, 0, stream>>>(h32, Wp, bp, (float*)d_out);
}

// Round 3
// 1819.688 us; speedup vs baseline: 1.5361x; 1.4407x over previous
//
#include <hip/hip_runtime.h>
#include <hip/hip_bf16.h>
#include <cstddef>
#include <cstdint>

#define NN 2048      // nodes (M and K of the big GEMMs)
#define CIN 2
#define HH 32        // hidden
#define EMB 16
#define HOR 12
#define BB 32        // batch
#define TT 16        // time steps
#define GC 128       // 4*HH gate channels
#define XCOLS 1024   // B*T*C
#define HCOLS 1024   // B*H  (GEMM N dim)
#define KSPLIT 4
#define KS (NN / KSPLIT)          // 512 per k-slice
#define CSZ ((size_t)NN * HCOLS)  // one partial C: 2M floats

typedef __attribute__((ext_vector_type(8))) short bf16x8;
typedef __attribute__((ext_vector_type(4))) float f32x4;
typedef unsigned short u16;

__device__ inline u16 f2bf(float f) {
    __hip_bfloat16 h = __float2bfloat16(f);
    return *reinterpret_cast<u16*>(&h);
}
__device__ inline float bf2f(u16 u) {
    __hip_bfloat16 h = *reinterpret_cast<__hip_bfloat16*>(&u);
    return __bfloat162float(h);
}
__device__ inline void split_bf(float v, u16& hi, u16& lo) {
    hi = f2bf(v);
    lo = f2bf(v - bf2f(hi));
}

// ---------------------------------------------------------------------------
// Kernel 1: A = softmax(relu(E1 @ E2^T)) row-wise -> bf16 hi/lo splits.
// ---------------------------------------------------------------------------
__global__ __launch_bounds__(256) void adj_softmax(const float* __restrict__ E1,
                                                   const float* __restrict__ E2,
                                                   u16* __restrict__ Ahi,
                                                   u16* __restrict__ Alo) {
    const int i = blockIdx.x;
    __shared__ float red[256];
    float e1[EMB];
#pragma unroll
    for (int k = 0; k < EMB; ++k) e1[k] = E1[i * EMB + k];

    float s[8];
    float mx = -1e30f;
#pragma unroll
    for (int q = 0; q < 8; ++q) {
        const int j = q * 256 + threadIdx.x;
        float d = 0.f;
#pragma unroll
        for (int k = 0; k < EMB; ++k) d += e1[k] * E2[j * EMB + k];
        d = fmaxf(d, 0.0f);
        s[q] = d;
        mx = fmaxf(mx, d);
    }
    red[threadIdx.x] = mx;
    __syncthreads();
    for (int off = 128; off > 0; off >>= 1) {
        if (threadIdx.x < off) red[threadIdx.x] = fmaxf(red[threadIdx.x], red[threadIdx.x + off]);
        __syncthreads();
    }
    mx = red[0];
    __syncthreads();

    float sum = 0.f;
#pragma unroll
    for (int q = 0; q < 8; ++q) { s[q] = expf(s[q] - mx); sum += s[q]; }
    red[threadIdx.x] = sum;
    __syncthreads();
    for (int off = 128; off > 0; off >>= 1) {
        if (threadIdx.x < off) red[threadIdx.x] += red[threadIdx.x + off];
        __syncthreads();
    }
    const float inv = 1.0f / red[0];
#pragma unroll
    for (int q = 0; q < 8; ++q) {
        const float v = s[q] * inv;
        u16 hi, lo; split_bf(v, hi, lo);
        const size_t off = (size_t)i * NN + q * 256 + threadIdx.x;
        Ahi[off] = hi; Alo[off] = lo;
    }
}

// ---------------------------------------------------------------------------
// Kernel 2: XT[col][node] bf16 hi/lo, col = (b*T+t)*C + c
// ---------------------------------------------------------------------------
__global__ __launch_bounds__(256) void transpose_x(const float* __restrict__ x,
                                                   u16* __restrict__ XTh,
                                                   u16* __restrict__ XTl) {
    const int idx = blockIdx.x * 256 + threadIdx.x;
    const int col = idx >> 11;
    const int j   = idx & (NN - 1);
    const int bt  = col >> 1;
    const int c   = col & 1;
    const float v = x[((size_t)bt * NN + j) * CIN + c];
    u16 hi, lo; split_bf(v, hi, lo);
    XTh[idx] = hi; XTl[idx] = lo;
}

// ---------------------------------------------------------------------------
// Kernel 3: split-K bf16x3 MFMA GEMM.
// Cp[ks][2048][1024] += A[.][ks-slice] * B[ks-slice][.] for ks = blockIdx.z
// 128x64 tile, BK=32, 256 threads (4 waves, each 64x32 of 16x16x32 MFMA).
// LDS 24KB: A hi/lo [kq(4)][row(128)][16B], B hi/lo [kq(4)][row(64)][16B].
// ---------------------------------------------------------------------------
__global__ __launch_bounds__(256, 4) void gemm3s(const u16* __restrict__ Ahi_,
                                                 const u16* __restrict__ Alo_,
                                                 const u16* __restrict__ Bhi_,
                                                 const u16* __restrict__ Blo_,
                                                 float* __restrict__ Cp) {
    __shared__ char smem[24576];
    const int tid  = threadIdx.x;
    const int w    = tid >> 6;
    const int lane = tid & 63;
    const int m0 = blockIdx.y * 128;
    const int n0 = blockIdx.x * 64;
    const int k0 = blockIdx.z * KS;

    // staging: 24 chunks of 1KB; wave w handles chunks w*6 .. w*6+5
    const u16* gsrc[6];
    int        ldst[6];
#pragma unroll
    for (int j = 0; j < 6; ++j) {
        const int ch = w * 6 + j;
        if (ch < 16) {             // A tile: s(2) x kq(4) x half(2)
            const int s    = ch >> 3;
            const int kq   = (ch >> 1) & 3;
            const int half = ch & 1;
            const u16* base = s ? Alo_ : Ahi_;
            gsrc[j] = base + (size_t)(m0 + half * 64 + lane) * NN + k0 + kq * 8;
            ldst[j] = s * 8192 + kq * 2048 + half * 1024 + lane * 16;
        } else {                   // B tile: s(2) x kq(4)
            const int c2 = ch - 16;
            const int s  = c2 >> 2;
            const int kq = c2 & 3;
            const u16* base = s ? Blo_ : Bhi_;
            gsrc[j] = base + (size_t)(n0 + lane) * NN + k0 + kq * 8;
            ldst[j] = 16384 + s * 4096 + kq * 1024 + lane * 16;
        }
    }

    const int q  = lane >> 4;
    const int mr = lane & 15;
    const int wr = (w >> 1) * 64;   // wave covers rows wr..wr+63
    const int wc = (w & 1) * 32;    // and cols wc..wc+31
    int aoff[4][2], boff[2][2];
#pragma unroll
    for (int i = 0; i < 4; ++i)
#pragma unroll
        for (int s = 0; s < 2; ++s)
            aoff[i][s] = s * 8192 + q * 2048 + (wr + i * 16 + mr) * 16;
#pragma unroll
    for (int j = 0; j < 2; ++j)
#pragma unroll
        for (int s = 0; s < 2; ++s)
            boff[j][s] = 16384 + s * 4096 + q * 1024 + (wc + j * 16 + mr) * 16;

    f32x4 acc[4][2];
#pragma unroll
    for (int i = 0; i < 4; ++i)
#pragma unroll
        for (int j = 0; j < 2; ++j) acc[i][j] = (f32x4)(0.0f);

    for (int it = 0; it < KS / 32; ++it) {
#pragma unroll
        for (int j = 0; j < 6; ++j) {
            __builtin_amdgcn_global_load_lds(
                (const __attribute__((address_space(1))) unsigned int*)(gsrc[j]),
                (__attribute__((address_space(3))) unsigned int*)(smem + ldst[j]), 16, 0, 0);
            gsrc[j] += 32;
        }
        __syncthreads();

        bf16x8 fa[4][2], fb[2][2];
#pragma unroll
        for (int i = 0; i < 4; ++i)
#pragma unroll
            for (int s = 0; s < 2; ++s)
                fa[i][s] = *reinterpret_cast<const bf16x8*>(smem + aoff[i][s]);
#pragma unroll
        for (int j = 0; j < 2; ++j)
#pragma unroll
            for (int s = 0; s < 2; ++s)
                fb[j][s] = *reinterpret_cast<const bf16x8*>(smem + boff[j][s]);

#pragma unroll
        for (int i = 0; i < 4; ++i)
#pragma unroll
            for (int j = 0; j < 2; ++j) {
                acc[i][j] = __builtin_amdgcn_mfma_f32_16x16x32_bf16(fa[i][0], fb[j][0], acc[i][j], 0, 0, 0);
                acc[i][j] = __builtin_amdgcn_mfma_f32_16x16x32_bf16(fa[i][0], fb[j][1], acc[i][j], 0, 0, 0);
                acc[i][j] = __builtin_amdgcn_mfma_f32_16x16x32_bf16(fa[i][1], fb[j][0], acc[i][j], 0, 0, 0);
            }
        __syncthreads();
    }

    float* Cs = Cp + (size_t)blockIdx.z * CSZ;
#pragma unroll
    for (int i = 0; i < 4; ++i)
#pragma unroll
        for (int j = 0; j < 2; ++j)
#pragma unroll
            for (int r = 0; r < 4; ++r) {
                const int row = m0 + wr + i * 16 + q * 4 + r;
                const int col = n0 + wc + j * 16 + mr;
                Cs[(size_t)row * HCOLS + col] = acc[i][j][r];
            }
}

// ---------------------------------------------------------------------------
// Kernel 3b: AX = sum of 4 k-slice partials (one-time, for the x path)
// ---------------------------------------------------------------------------
__global__ __launch_bounds__(256) void reduce_ax(const float* __restrict__ P,
                                                 float* __restrict__ AX) {
    const size_t idx = (size_t)blockIdx.x * 256 + threadIdx.x;  // over CSZ/4 float4
    const float4* P4 = (const float4*)P;
    const size_t q = CSZ / 4;
    float4 a = P4[idx], b = P4[idx + q], c = P4[idx + 2 * q], d = P4[idx + 3 * q];
    float4 r;
    r.x = a.x + b.x + c.x + d.x;
    r.y = a.y + b.y + c.y + d.y;
    r.z = a.z + b.z + c.z + d.z;
    r.w = a.w + b.w + c.w + d.w;
    ((float4*)AX)[idx] = r;
}

// ---------------------------------------------------------------------------
// Kernel 3c: weight prep. Whr[k][h][g] = Wh[k][g*32+h]; Wxr[c][h][g]; bfold.
// ---------------------------------------------------------------------------
__global__ __launch_bounds__(256) void prep_weights(const float* __restrict__ Wx,
                                                    const float* __restrict__ bx,
                                                    const float* __restrict__ Wh,
                                                    const float* __restrict__ bh,
                                                    float* __restrict__ Whr,
                                                    float* __restrict__ Wxr,
                                                    float* __restrict__ bfold) {
    const int tid = threadIdx.x;
#pragma unroll
    for (int r = 0; r < 16; ++r) {
        const int idx = tid * 16 + r;           // 4096
        const int k = idx >> 7, rem = idx & 127;
        const int h = rem >> 2, g = rem & 3;
        Whr[idx] = Wh[k * GC + g * HH + h];
    }
    {
        const int idx = tid;                    // 256
        const int c = idx >> 7, rem = idx & 127;
        const int h = rem >> 2, g = rem & 3;
        Wxr[idx] = Wx[c * GC + g * HH + h];
    }
    if (tid < 128) {
        const int h = tid >> 2, g = tid & 3;
        bfold[tid] = bx[g * HH + h] + bh[g * HH + h];
    }
}

// ---------------------------------------------------------------------------
// Kernel 4: gates + cell update, 64 nodes x 1 batch per block.
// Reads 4 k-slice partials of Ah inline. Whr broadcast from LDS.
// ---------------------------------------------------------------------------
__global__ __launch_bounds__(256) void gate_update(const float* __restrict__ AX,   // [NN][XCOLS] (reduced)
                                                   const float* __restrict__ Ahp,  // 4 x [NN][HCOLS] partials
                                                   const float* __restrict__ Whr,  // [32][32][4]
                                                   const float* __restrict__ Wxr,  // [2][32][4]
                                                   const float* __restrict__ bfold,// [32][4]
                                                   float* __restrict__ c,          // [NN][HCOLS]
                                                   float* __restrict__ h32,        // [NN][HCOLS]
                                                   u16* __restrict__ hTh,          // [HCOLS][NN]
                                                   u16* __restrict__ hTl,
                                                   int t, int first) {
    const int n0 = blockIdx.x * 64;
    const int b  = blockIdx.y;
    const int tid = threadIdx.x;
    __shared__ float whr[4096];
    __shared__ float wxr[256];
    __shared__ float bfl[128];
    __shared__ float ah_s[64][33];
    __shared__ float axs[2][64];

    // stage weights (L2-resident after first block)
#pragma unroll
    for (int r = 0; r < 4; ++r)
        *(float4*)&whr[(tid * 4 + r * 1024)] = *(const float4*)&Whr[(tid * 4 + r * 1024)];
    if (tid < 64)  *(float4*)&wxr[tid * 4] = *(const float4*)&Wxr[tid * 4];
    if (tid < 32)  *(float4*)&bfl[tid * 4] = *(const float4*)&bfold[tid * 4];

    if (!first) {
        const int nl = tid >> 2;
        const int kq = (tid & 3) * 8;
        float4 a0 = make_float4(0, 0, 0, 0), a1 = make_float4(0, 0, 0, 0);
#pragma unroll
        for (int s = 0; s < KSPLIT; ++s) {
            const float* src = Ahp + s * CSZ + (size_t)(n0 + nl) * HCOLS + b * HH + kq;
            const float4 v0 = *(const float4*)src;
            const float4 v1 = *(const float4*)(src + 4);
            a0.x += v0.x; a0.y += v0.y; a0.z += v0.z; a0.w += v0.w;
            a1.x += v1.x; a1.y += v1.y; a1.z += v1.z; a1.w += v1.w;
        }
        ah_s[nl][kq + 0] = a0.x; ah_s[nl][kq + 1] = a0.y;
        ah_s[nl][kq + 2] = a0.z; ah_s[nl][kq + 3] = a0.w;
        ah_s[nl][kq + 4] = a1.x; ah_s[nl][kq + 5] = a1.y;
        ah_s[nl][kq + 6] = a1.z; ah_s[nl][kq + 7] = a1.w;
    }
    if (tid < 128) {
        const int which = tid >> 6, nl = tid & 63;
        axs[which][nl] = AX[(size_t)(n0 + nl) * XCOLS + (b * TT + t) * CIN + which];
    }
    __syncthreads();

    const int nl = tid & 63;
    const int hq = tid >> 6;     // handles h-units hq*8 .. hq*8+7
    const float ax0 = axs[0][nl], ax1 = axs[1][nl];

    float acc[8][4];
#pragma unroll
    for (int u = 0; u < 8; ++u) {
        const int h = hq * 8 + u;
#pragma unroll
        for (int g = 0; g < 4; ++g)
            acc[u][g] = bfl[h * 4 + g] + ax0 * wxr[h * 4 + g] + ax1 * wxr[128 + h * 4 + g];
    }
    if (!first) {
        float ah_r[HH];
#pragma unroll
        for (int k = 0; k < HH; ++k) ah_r[k] = ah_s[nl][k];
#pragma unroll 4
        for (int k = 0; k < HH; ++k) {
            const float a = ah_r[k];
#pragma unroll
            for (int u = 0; u < 8; ++u) {
                const float* wp = &whr[(k * HH + hq * 8 + u) * 4];
                acc[u][0] += a * wp[0];
                acc[u][1] += a * wp[1];
                acc[u][2] += a * wp[2];
                acc[u][3] += a * wp[3];
            }
        }
    }

    float cn[8], hn[8];
    const size_t off = (size_t)(n0 + nl) * HCOLS + b * HH + hq * 8;
    float4 c0o = make_float4(0, 0, 0, 0), c1o = make_float4(0, 0, 0, 0);
    if (!first) { c0o = *(const float4*)(c + off); c1o = *(const float4*)(c + off + 4); }
    const float cold[8] = {c0o.x, c0o.y, c0o.z, c0o.w, c1o.x, c1o.y, c1o.z, c1o.w};
#pragma unroll
    for (int u = 0; u < 8; ++u) {
        const float i_ = 1.0f / (1.0f + expf(-acc[u][0]));
        const float f_ = 1.0f / (1.0f + expf(-acc[u][1]));
        const float o_ = 1.0f / (1.0f + expf(-acc[u][2]));
        const float g_ = tanhf(acc[u][3]);
        const float c_t = f_ * cold[u] + i_ * g_;
        cn[u] = c_t;
        hn[u] = o_ * tanhf(c_t);
    }
    *(float4*)(c + off)       = make_float4(cn[0], cn[1], cn[2], cn[3]);
    *(float4*)(c + off + 4)   = make_float4(cn[4], cn[5], cn[6], cn[7]);
    *(float4*)(h32 + off)     = make_float4(hn[0], hn[1], hn[2], hn[3]);
    *(float4*)(h32 + off + 4) = make_float4(hn[4], hn[5], hn[6], hn[7]);
#pragma unroll
    for (int u = 0; u < 8; ++u) {
        u16 hh, hl; split_bf(hn[u], hh, hl);
        const size_t toff = (size_t)(b * HH + hq * 8 + u) * NN + n0 + nl;
        hTh[toff] = hh; hTl[toff] = hl;
    }
}

// ---------------------------------------------------------------------------
// Kernel 5: out[b][th][n] = bp[th] + sum_k h[n][b*H+k] * Wp[k][th]
// ---------------------------------------------------------------------------
__global__ __launch_bounds__(256) void head_kernel(const float* __restrict__ h,
                                                   const float* __restrict__ Wp,
                                                   const float* __restrict__ bp,
                                                   float* __restrict__ out) {
    const int idx = blockIdx.x * 256 + threadIdx.x;
    const int b = idx >> 11;
    const int n = idx & (NN - 1);
    float hv[HH];
    const float* hp = h + (size_t)n * HCOLS + b * HH;
#pragma unroll
    for (int k = 0; k < HH; ++k) hv[k] = hp[k];
#pragma unroll
    for (int th = 0; th < HOR; ++th) {
        float acc = bp[th];
#pragma unroll
        for (int k = 0; k < HH; ++k) acc += hv[k] * Wp[k * HOR + th];
        out[((size_t)b * HOR + th) * NN + n] = acc;
    }
}

// ---------------------------------------------------------------------------
extern "C" void kernel_launch(void* const* d_in, const int* in_sizes, int n_in,
                              void* d_out, int out_size, void* d_ws, size_t ws_size,
                              hipStream_t stream) {
    const float* x  = (const float*)d_in[0];
    const float* E1 = (const float*)d_in[1];
    const float* E2 = (const float*)d_in[2];
    const float* Wx = (const float*)d_in[3];
    const float* bx = (const float*)d_in[4];
    const float* Wh = (const float*)d_in[5];
    const float* bh = (const float*)d_in[6];
    const float* Wp = (const float*)d_in[7];
    const float* bp = (const float*)d_in[8];

    char* ws = (char*)d_ws;
    u16*   A_hi = (u16*)(ws);                         //  8 MB
    u16*   A_lo = (u16*)(ws + (8ull  << 20));         //  8 MB
    u16*   XTh  = (u16*)(ws + (16ull << 20));         //  4 MB (reused as hTh)
    u16*   XTl  = (u16*)(ws + (20ull << 20));         //  4 MB (reused as hTl)
    float* P    = (float*)(ws + (24ull << 20));       // 32 MB (4 k-slice partials)
    float* AX   = (float*)(ws + (56ull << 20));       //  8 MB
    float* cst  = (float*)(ws + (64ull << 20));       //  8 MB
    float* h32  = (float*)(ws + (72ull << 20));       //  8 MB
    float* Whr  = (float*)(ws + (80ull << 20));       // 16 KB
    float* Wxr  = (float*)(ws + (80ull << 20) + 65536);
    float* bfold= (float*)(ws + (80ull << 20) + 131072);
    u16*   hTh  = XTh;
    u16*   hTl  = XTl;

    adj_softmax<<<NN, 256, 0, stream>>>(E1, E2, A_hi, A_lo);
    transpose_x<<<(XCOLS * NN) / 256, 256, 0, stream>>>(x, XTh, XTl);
    prep_weights<<<1, 256, 0, stream>>>(Wx, bx, Wh, bh, Whr, Wxr, bfold);

    dim3 gg(HCOLS / 64, NN / 128, KSPLIT);   // 16 x 16 x 4 = 1024 blocks
    gemm3s<<<gg, 256, 0, stream>>>(A_hi, A_lo, XTh, XTl, P);
    reduce_ax<<<(int)(CSZ / 4 / 256), 256, 0, stream>>>(P, AX);

    for (int t = 0; t < TT; ++t) {
        if (t > 0)
            gemm3s<<<gg, 256, 0, stream>>>(A_hi, A_lo, hTh, hTl, P);
        gate_update<<<dim3(NN / 64, BB), 256, 0, stream>>>(AX, P, Whr, Wxr, bfold,
                                                           cst, h32, hTh, hTl, t, t == 0 ? 1 : 0);
    }

    head_kernel<<<(BB * NN) / 256, 256, 0, stream>>>(h32, Wp, bp, (float*)d_out);
}